// Round 1
// baseline (741.111 us; speedup 1.0000x reference)
//
#include <hip/hip_runtime.h>

#define NPIX (8*128*128)   // 131072 pixels
#define CH   256
#define P    64            // pixels per block

// Fused SIREN MLP: 12 -> 256 -> 256 -> 3, sin activations, out = z + 0.5*sin(...)
// Block: 256 threads = 4 waves. Each block owns P=64 pixels (lane = pixel).
// Each wave owns a 64-channel chunk for layers 1/2; layer-4 partials reduced in LDS.
// W1/W2/b* are read via wave-uniform indices -> scalar (s_load) path feeds the
// SGPR operand of v_fmac_f32, so layer 2 is ~1 FMA instruction per MAC.
__global__ __launch_bounds__(256, 2) void rendernet_f32(
    const float* __restrict__ z,
    const float* __restrict__ nrm,
    const float* __restrict__ sph,
    const float* __restrict__ pc,
    const float* __restrict__ vd,
    const float* __restrict__ W1,
    const float* __restrict__ b1,
    const float* __restrict__ W2,
    const float* __restrict__ b2,
    const float* __restrict__ W4,
    const float* __restrict__ b4,
    float* __restrict__ out)
{
    __shared__ float h1_s[CH][P];      // 64 KB
    __shared__ float red_s[4][3][P];   // 3 KB

    const int tid  = threadIdx.x;
    const int lane = tid & 63;
    const int wave = tid >> 6;
    const int o0   = __builtin_amdgcn_readfirstlane(wave * 64);
    const int p    = blockIdx.x * P + lane;

    // ---- load the 12 input channels for this pixel (coalesced) ----
    float xv[12];
    #pragma unroll
    for (int k = 0; k < 3; ++k) xv[k]     = sph[k*NPIX + p];
    #pragma unroll
    for (int k = 0; k < 3; ++k) xv[3 + k] = nrm[k*NPIX + p];
    #pragma unroll
    for (int k = 0; k < 3; ++k) xv[6 + k] = pc [k*NPIX + p];
    #pragma unroll
    for (int k = 0; k < 3; ++k) xv[9 + k] = vd [k*NPIX + p];

    // ---- layer 1: this wave computes channels [o0, o0+64) for its 64 pixels ----
    for (int ii = 0; ii < 64; ++ii) {
        const int i = o0 + ii;                     // wave-uniform channel index
        float a = b1[i];
        #pragma unroll
        for (int k = 0; k < 12; ++k) a += W1[i*12 + k] * xv[k];
        h1_s[i][lane] = __sinf(30.0f * a);
    }
    __syncthreads();

    // ---- layer 2: wave computes channels [o0, o0+64) over K=256 ----
    float acc[64];
    #pragma unroll
    for (int j = 0; j < 64; ++j) acc[j] = b2[o0 + j];

    for (int ic = 0; ic < CH; ic += 16) {
        float h[16];
        #pragma unroll
        for (int t = 0; t < 16; ++t) h[t] = h1_s[ic + t][lane];
        #pragma unroll
        for (int t = 0; t < 16; ++t) {
            #pragma unroll
            for (int j = 0; j < 64; ++j) {
                acc[j] += W2[(o0 + j)*CH + ic + t] * h[t];   // s_load * vgpr
            }
        }
    }

    // ---- layer 2 activation + partial layer 4 ----
    float a40 = 0.f, a41 = 0.f, a42 = 0.f;
    #pragma unroll
    for (int j = 0; j < 64; ++j) {
        const float h2 = __sinf(30.0f * acc[j]);
        a40 += W4[0*CH + o0 + j] * h2;
        a41 += W4[1*CH + o0 + j] * h2;
        a42 += W4[2*CH + o0 + j] * h2;
    }
    red_s[wave][0][lane] = a40;
    red_s[wave][1][lane] = a41;
    red_s[wave][2][lane] = a42;
    __syncthreads();

    // ---- cross-wave reduce + layer-4 activation + residual ----
    if (wave == 0) {
        #pragma unroll
        for (int c = 0; c < 3; ++c) {
            const float t = red_s[0][c][lane] + red_s[1][c][lane]
                          + red_s[2][c][lane] + red_s[3][c][lane];
            out[c*NPIX + p] = z[c*NPIX + p] + 0.5f * __sinf(30.0f * (t + b4[c]));
        }
    }
}

extern "C" void kernel_launch(void* const* d_in, const int* in_sizes, int n_in,
                              void* d_out, int out_size, void* d_ws, size_t ws_size,
                              hipStream_t stream) {
    const float* z   = (const float*)d_in[0];
    const float* nrm = (const float*)d_in[1];
    // d_in[2] = ad : unused by the reference
    const float* s   = (const float*)d_in[3];
    const float* pc  = (const float*)d_in[4];
    const float* vd  = (const float*)d_in[5];
    const float* W1  = (const float*)d_in[6];
    const float* b1  = (const float*)d_in[7];
    const float* W2  = (const float*)d_in[8];
    const float* b2  = (const float*)d_in[9];
    const float* W4  = (const float*)d_in[10];
    const float* b4  = (const float*)d_in[11];
    float* out = (float*)d_out;

    dim3 grid(NPIX / P);   // 2048 blocks
    dim3 block(256);
    rendernet_f32<<<grid, block, 0, stream>>>(z, nrm, s, pc, vd,
                                              W1, b1, W2, b2, W4, b4, out);
}

// Round 2
// 172.981 us; speedup vs baseline: 4.2843x; 4.2843x over previous
//
#include <hip/hip_runtime.h>

#define NPIX (8*128*128)   // 131072 pixels
#define CH   256

typedef __attribute__((ext_vector_type(8))) short bf16x8;
typedef __attribute__((ext_vector_type(4))) float f32x4;

__device__ inline unsigned short f2bf(float f) {
    unsigned int u = __float_as_uint(f);
    return (unsigned short)((u + 0x7FFFu + ((u >> 16) & 1u)) >> 16);  // RNE
}

// W2 (256x256 f32) -> bf16 into workspace, once per launch
__global__ __launch_bounds__(256) void conv_w2_kernel(const float* __restrict__ W2,
                                                      unsigned short* __restrict__ W2b) {
    const int i = blockIdx.x * 256 + threadIdx.x;   // 256 blocks x 256 thr = 65536
    W2b[i] = f2bf(W2[i]);
}

// Fused SIREN: 12 -> 256 (fp32 VALU) -> 256 (bf16 MFMA) -> 3 (fp32), out = z + 0.5*sin
// Block: 256 thr = 4 waves, 64 pixels. Wave w owns out-ch [64w, 64w+64).
// h1 in LDS as bf16 [64 pix][256 k], XOR-swizzled (byte ^= (row&7)<<4) so the
// stride-512B A-fragment column reads don't bank-conflict. h2 reuses the same
// LDS (fp32, stride 1024B, same XOR) after a barrier.
template<bool PRECONV>
__global__ __launch_bounds__(256, 2) void rendernet_mfma(
    const float* __restrict__ z,
    const float* __restrict__ nrm,
    const float* __restrict__ sph,
    const float* __restrict__ pc,
    const float* __restrict__ vd,
    const float* __restrict__ W1,
    const float* __restrict__ b1,
    const float* __restrict__ W2f,
    const unsigned short* __restrict__ W2b,
    const float* __restrict__ b2,
    const float* __restrict__ W4,
    const float* __restrict__ b4,
    float* __restrict__ out)
{
    __shared__ char smem[64*1024 + 4*3*64*4];       // 64KB h1/h2 union + 3KB reduce
    float* red_s = (float*)(smem + 64*1024);        // [wave][3][64]

    const int tid     = threadIdx.x;
    const int lane    = tid & 63;
    const int wave    = tid >> 6;
    const int pixbase = blockIdx.x * 64;

    // ---------------- layer 1 (fp32 vector): thread = (pixel, 64-ch chunk) ----------------
    {
        const int p   = tid & 63;
        const int c0  = (tid >> 6) * 64;            // wave-uniform
        const int gp  = pixbase + p;
        const int swz = (p & 7) << 4;

        float xv[12];
        #pragma unroll
        for (int k = 0; k < 3; ++k) xv[k]     = sph[k*NPIX + gp];
        #pragma unroll
        for (int k = 0; k < 3; ++k) xv[3 + k] = nrm[k*NPIX + gp];
        #pragma unroll
        for (int k = 0; k < 3; ++k) xv[6 + k] = pc [k*NPIX + gp];
        #pragma unroll
        for (int k = 0; k < 3; ++k) xv[9 + k] = vd [k*NPIX + gp];

        #pragma unroll
        for (int cc = 0; cc < 64; cc += 8) {
            bf16x8 pk;
            #pragma unroll
            for (int u = 0; u < 8; ++u) {
                const int c = c0 + cc + u;          // wave-uniform -> scalar W1/b1 loads
                float a = b1[c];
                #pragma unroll
                for (int k = 0; k < 12; ++k) a += W1[c*12 + k] * xv[k];
                pk[u] = (short)f2bf(__sinf(30.0f * a));
            }
            *(bf16x8*)(smem + p*512 + (((c0 + cc)*2) ^ swz)) = pk;
        }
    }
    __syncthreads();

    // ---------------- layer 2 (bf16 MFMA): wave = 64 pix x 64 out-ch, K=256 ----------------
    const int lm = lane & 15;     // frag row (A) / col (B,D)
    const int lg = lane >> 4;     // k-group of 8 (A,B) / row-group of 4 (D)
    const int n0 = wave * 64;     // wave's out-ch base

    f32x4 acc[4][4];
    #pragma unroll
    for (int i = 0; i < 4; ++i)
        #pragma unroll
        for (int j = 0; j < 4; ++j) acc[i][j] = (f32x4){0.f, 0.f, 0.f, 0.f};

    const unsigned short* wpb = W2b + (n0 + lm)*CH + lg*8;
    const float*          wpf = W2f + (n0 + lm)*CH + lg*8;

    #pragma unroll
    for (int k0 = 0; k0 < CH; k0 += 32) {
        bf16x8 bfr[4];
        #pragma unroll
        for (int nf = 0; nf < 4; ++nf) {
            if (PRECONV) {
                bfr[nf] = *(const bf16x8*)(wpb + nf*16*CH + k0);
            } else {
                f32x4 lo = *(const f32x4*)(wpf + nf*16*CH + k0);
                f32x4 hi = *(const f32x4*)(wpf + nf*16*CH + k0 + 4);
                bf16x8 t;
                #pragma unroll
                for (int u = 0; u < 4; ++u) { t[u] = (short)f2bf(lo[u]); t[4+u] = (short)f2bf(hi[u]); }
                bfr[nf] = t;
            }
        }
        bf16x8 afr[4];
        #pragma unroll
        for (int mf = 0; mf < 4; ++mf) {
            const int pr = mf*16 + lm;
            afr[mf] = *(const bf16x8*)(smem + pr*512 + (((k0 + lg*8)*2) ^ ((pr & 7) << 4)));
        }
        #pragma unroll
        for (int mf = 0; mf < 4; ++mf)
            #pragma unroll
            for (int nf = 0; nf < 4; ++nf)
                acc[mf][nf] = __builtin_amdgcn_mfma_f32_16x16x32_bf16(
                                  afr[mf], bfr[nf], acc[mf][nf], 0, 0, 0);
    }
    __syncthreads();   // all h1 reads done; smem can be reused for h2

    // ---------------- layer 2 epilogue: h2 = sin(30*(acc+b2)) -> swizzled LDS ----------------
    float b2v[4];
    #pragma unroll
    for (int nf = 0; nf < 4; ++nf) b2v[nf] = b2[n0 + nf*16 + lm];

    #pragma unroll
    for (int mf = 0; mf < 4; ++mf)
        #pragma unroll
        for (int nf = 0; nf < 4; ++nf)
            #pragma unroll
            for (int r = 0; r < 4; ++r) {
                const int prow = mf*16 + lg*4 + r;          // D row = pixel
                const int col  = n0 + nf*16 + lm;           // D col = out-ch
                const float hv = __sinf(30.0f * (acc[mf][nf][r] + b2v[nf]));
                *(float*)(smem + prow*1024 + ((col*4) ^ ((prow & 7) << 4))) = hv;
            }
    __syncthreads();

    // ---------------- layer 4 (fp32): thread = (pixel, 64-oc chunk) ----------------
    {
        const int p   = tid & 63;
        const int c0  = (tid >> 6) * 64;                    // wave-uniform -> scalar W4 loads
        const int swz = (p & 7) << 4;
        float a0 = 0.f, a1 = 0.f, a2 = 0.f;
        #pragma unroll
        for (int c = 0; c < 64; c += 4) {
            f32x4 hv = *(const f32x4*)(smem + p*1024 + (((c0 + c)*4) ^ swz));
            #pragma unroll
            for (int e = 0; e < 4; ++e) {
                const int oc = c0 + c + e;
                a0 += W4[0*CH + oc] * hv[e];
                a1 += W4[1*CH + oc] * hv[e];
                a2 += W4[2*CH + oc] * hv[e];
            }
        }
        red_s[(wave*3 + 0)*64 + p] = a0;
        red_s[(wave*3 + 1)*64 + p] = a1;
        red_s[(wave*3 + 2)*64 + p] = a2;
    }
    __syncthreads();

    // ---------------- cross-wave reduce + residual ----------------
    if (wave == 0) {
        #pragma unroll
        for (int c3 = 0; c3 < 3; ++c3) {
            const float t = red_s[(0*3 + c3)*64 + lane] + red_s[(1*3 + c3)*64 + lane]
                          + red_s[(2*3 + c3)*64 + lane] + red_s[(3*3 + c3)*64 + lane];
            const int gi = c3*NPIX + pixbase + lane;
            out[gi] = z[gi] + 0.5f * __sinf(30.0f * (t + b4[c3]));
        }
    }
}

extern "C" void kernel_launch(void* const* d_in, const int* in_sizes, int n_in,
                              void* d_out, int out_size, void* d_ws, size_t ws_size,
                              hipStream_t stream) {
    const float* z   = (const float*)d_in[0];
    const float* nrm = (const float*)d_in[1];
    // d_in[2] = ad : unused by the reference
    const float* s   = (const float*)d_in[3];
    const float* pc  = (const float*)d_in[4];
    const float* vd  = (const float*)d_in[5];
    const float* W1  = (const float*)d_in[6];
    const float* b1  = (const float*)d_in[7];
    const float* W2  = (const float*)d_in[8];
    const float* b2  = (const float*)d_in[9];
    const float* W4  = (const float*)d_in[10];
    const float* b4  = (const float*)d_in[11];
    float* out = (float*)d_out;

    dim3 grid(NPIX / 64);   // 2048 blocks
    dim3 block(256);

    if (ws_size >= (size_t)(CH*CH*sizeof(unsigned short))) {
        unsigned short* W2b = (unsigned short*)d_ws;
        conv_w2_kernel<<<dim3(CH*CH/256), block, 0, stream>>>(W2, W2b);
        rendernet_mfma<true><<<grid, block, 0, stream>>>(z, nrm, s, pc, vd,
                                                         W1, b1, W2, W2b, b2, W4, b4, out);
    } else {
        rendernet_mfma<false><<<grid, block, 0, stream>>>(z, nrm, s, pc, vd,
                                                          W1, b1, W2, nullptr, b2, W4, b4, out);
    }
}